// Round 1
// baseline (1709.575 us; speedup 1.0000x reference)
//
#include <hip/hip_runtime.h>
#include <cstdint>
#include <cstddef>

#define U_CNT 100000
#define I_CNT 50000
#define D_DIM 64
#define N_CNT (U_CNT + I_CNT)
#define NNZ_CNT 4000000
#define EPS_F 0.2f

// ---------------- concat user_emb | item_emb -> x0 ----------------
__global__ void concat_kernel(const float* __restrict__ ue,
                              const float* __restrict__ ie,
                              float* __restrict__ x) {
    size_t i = (size_t)blockIdx.x * blockDim.x + threadIdx.x;
    const size_t n4  = (size_t)N_CNT * D_DIM / 4;
    const size_t ud4 = (size_t)U_CNT * D_DIM / 4;
    if (i >= n4) return;
    float4 v = (i < ud4) ? ((const float4*)ue)[i] : ((const float4*)ie)[i - ud4];
    ((float4*)x)[i] = v;
}

// ---------------- CSR build: histogram ----------------
__global__ void hist_kernel(const int* __restrict__ rows, int* __restrict__ deg) {
    int e = blockIdx.x * blockDim.x + threadIdx.x;
    if (e < NNZ_CNT) atomicAdd(&deg[rows[e]], 1);
}

// ---------------- CSR build: single-block exclusive scan ----------------
__global__ void scan_kernel(const int* __restrict__ deg, int* __restrict__ rowptr) {
    __shared__ int lds[1024];
    const int t = threadIdx.x;
    const int C = (N_CNT + 1023) / 1024;  // 147
    int base = t * C;
    int s = 0;
    for (int j = 0; j < C; ++j) {
        int i = base + j;
        if (i < N_CNT) s += deg[i];
    }
    lds[t] = s;
    __syncthreads();
    // Hillis-Steele inclusive scan (read, barrier, write, barrier)
    for (int off = 1; off < 1024; off <<= 1) {
        int v = (t >= off) ? lds[t - off] : 0;
        __syncthreads();
        lds[t] += v;
        __syncthreads();
    }
    int ex = (t > 0) ? lds[t - 1] : 0;
    for (int j = 0; j < C; ++j) {
        int i = base + j;
        if (i < N_CNT) { rowptr[i] = ex; ex += deg[i]; }
    }
    if (t == 1023) rowptr[N_CNT] = lds[1023];
}

// ---------------- CSR build: scatter ----------------
__global__ void scatter_kernel(const int* __restrict__ rows, const int* __restrict__ cols,
                               const float* __restrict__ vals,
                               const int* __restrict__ rowptr, int* __restrict__ cursor,
                               int* __restrict__ ccols, float* __restrict__ cvals) {
    int e = blockIdx.x * blockDim.x + threadIdx.x;
    if (e >= NNZ_CNT) return;
    int r = rows[e];
    int pos = rowptr[r] + atomicAdd(&cursor[r], 1);
    ccols[pos] = cols[e];
    cvals[pos] = vals[e];
}

// ---------------- fused SpMM + noise + accumulate ----------------
// one wave (64 lanes) per row; lane = feature dim
// mode 0: xnext = ego; acc_out = ego            (layer 0; xnext is the cl output)
// mode 1: xnext = ego; acc_out += ego           (layer 1)
// mode 2: acc_out = (acc_out + ego) / 3         (layer 2)
__global__ __launch_bounds__(256) void layer_kernel(
    const int* __restrict__ rowptr, const int* __restrict__ ccols,
    const float* __restrict__ cvals, const float* __restrict__ xin,
    const float* __restrict__ noise_k, float* __restrict__ xnext,
    float* __restrict__ acc_out, int mode) {
    const int lane = threadIdx.x & 63;
    const int r = blockIdx.x * 4 + (threadIdx.x >> 6);
    if (r >= N_CNT) return;
    const int start = rowptr[r];
    const int end   = rowptr[r + 1];

    float acc = 0.f;
    for (int base = start; base < end; base += 64) {
        int e = base + lane;
        int c = 0; float v = 0.f;
        if (e < end) { c = ccols[e]; v = cvals[e]; }
        int cnt = min(64, end - base);
        for (int j = 0; j < cnt; ++j) {
            int   cj = __shfl(c, j);
            float vj = __shfl(v, j);
            acc += vj * xin[(size_t)cj * D_DIM + lane];
        }
    }

    // normalized noise
    float nz = noise_k[(size_t)r * D_DIM + lane];
    float sq = nz * nz;
    #pragma unroll
    for (int off = 32; off > 0; off >>= 1) sq += __shfl_xor(sq, off);
    float inv = 1.f / fmaxf(sqrtf(sq), 1e-12f);
    nz *= inv;

    float sgn = (acc > 0.f) ? 1.f : ((acc < 0.f) ? -1.f : 0.f);
    float ego = acc + sgn * nz * EPS_F;

    size_t oi = (size_t)r * D_DIM + lane;
    if (mode == 0)      { xnext[oi] = ego; acc_out[oi] = ego; }
    else if (mode == 1) { xnext[oi] = ego; acc_out[oi] += ego; }
    else                { acc_out[oi] = (acc_out[oi] + ego) * (1.f / 3.f); }
}

extern "C" void kernel_launch(void* const* d_in, const int* in_sizes, int n_in,
                              void* d_out, int out_size, void* d_ws, size_t ws_size,
                              hipStream_t stream) {
    const float* ue    = (const float*)d_in[0];
    const float* ie    = (const float*)d_in[1];
    const int*   rows  = (const int*)d_in[2];
    const int*   cols  = (const int*)d_in[3];
    const float* vals  = (const float*)d_in[4];
    const float* noise = (const float*)d_in[5];
    float* out = (float*)d_out;
    char*  ws  = (char*)d_ws;

    auto align16 = [](size_t x) { return (x + 15) & ~(size_t)15; };
    size_t off = 0;
    int*   rowptr = (int*)(ws + off);  off = align16(off + (size_t)(N_CNT + 1) * 4);
    int*   cursor = (int*)(ws + off);  off = align16(off + (size_t)N_CNT * 4);
    int*   ccols  = (int*)(ws + off);  off = align16(off + (size_t)NNZ_CNT * 4);
    float* cvals  = (float*)(ws + off); off = align16(off + (size_t)NNZ_CNT * 4);
    float* bufA   = (float*)(ws + off); off += (size_t)N_CNT * D_DIM * 4;
    (void)ws_size; (void)in_sizes; (void)n_in; (void)out_size;

    const size_t ND = (size_t)N_CNT * D_DIM;
    float* cl = out + ND;  // ego_cl region; also serves as layer-0 output / layer-1 input

    // x0 = concat(user_emb, item_emb)
    concat_kernel<<<(int)((ND / 4 + 255) / 256), 256, 0, stream>>>(ue, ie, bufA);

    // CSR build
    hipMemsetAsync(cursor, 0, (size_t)N_CNT * 4, stream);
    hist_kernel<<<(NNZ_CNT + 255) / 256, 256, 0, stream>>>(rows, cursor);
    scan_kernel<<<1, 1024, 0, stream>>>(cursor, rowptr);
    hipMemsetAsync(cursor, 0, (size_t)N_CNT * 4, stream);
    scatter_kernel<<<(NNZ_CNT + 255) / 256, 256, 0, stream>>>(rows, cols, vals, rowptr,
                                                              cursor, ccols, cvals);

    // 3 propagation layers (fused spmm + noise + accumulate)
    int blocks = (N_CNT + 3) / 4;
    layer_kernel<<<blocks, 256, 0, stream>>>(rowptr, ccols, cvals, bufA, noise + 0 * ND,
                                             cl, out, 0);
    layer_kernel<<<blocks, 256, 0, stream>>>(rowptr, ccols, cvals, cl,   noise + 1 * ND,
                                             bufA, out, 1);
    layer_kernel<<<blocks, 256, 0, stream>>>(rowptr, ccols, cvals, bufA, noise + 2 * ND,
                                             nullptr, out, 2);
}

// Round 2
// 1347.800 us; speedup vs baseline: 1.2684x; 1.2684x over previous
//
#include <hip/hip_runtime.h>
#include <cstdint>
#include <cstddef>

#define U_CNT 100000
#define I_CNT 50000
#define D_DIM 64
#define N_CNT (U_CNT + I_CNT)
#define NNZ_CNT 4000000
#define EPS_F 0.2f
#define SCAN_TILE 1024
#define N_TILES ((N_CNT + SCAN_TILE - 1) / SCAN_TILE)   // 147

// ---------------- concat user_emb | item_emb -> x0 ----------------
__global__ void concat_kernel(const float* __restrict__ ue,
                              const float* __restrict__ ie,
                              float* __restrict__ x) {
    size_t i = (size_t)blockIdx.x * blockDim.x + threadIdx.x;
    const size_t n4  = (size_t)N_CNT * D_DIM / 4;
    const size_t ud4 = (size_t)U_CNT * D_DIM / 4;
    if (i >= n4) return;
    float4 v = (i < ud4) ? ((const float4*)ue)[i] : ((const float4*)ie)[i - ud4];
    ((float4*)x)[i] = v;
}

// ---------------- CSR build: histogram (4 edges/thread) ----------------
__global__ void hist_kernel(const int* __restrict__ rows, int* __restrict__ deg) {
    int t = blockIdx.x * blockDim.x + threadIdx.x;
    if (t >= NNZ_CNT / 4) return;
    int4 r4 = ((const int4*)rows)[t];
    atomicAdd(&deg[r4.x], 1);
    atomicAdd(&deg[r4.y], 1);
    atomicAdd(&deg[r4.z], 1);
    atomicAdd(&deg[r4.w], 1);
}

// ---------------- hierarchical scan, stage 1: per-tile scan ----------------
// Each block scans a 1024-elem tile of deg into rowptr (tile-local exclusive),
// writes the tile total, and ZEROES deg (so deg can be reused as scatter cursor).
__global__ __launch_bounds__(256) void partial_scan_kernel(
    int* __restrict__ deg, int* __restrict__ rowptr, int* __restrict__ tileSums) {
    __shared__ int lds[256];
    const int t = threadIdx.x;
    const int gbase = blockIdx.x * SCAN_TILE + t * 4;
    int v[4];
    int s = 0;
    #pragma unroll
    for (int j = 0; j < 4; ++j) {
        int i = gbase + j;
        v[j] = (i < N_CNT) ? deg[i] : 0;
        if (i < N_CNT) deg[i] = 0;
        s += v[j];
    }
    lds[t] = s;
    __syncthreads();
    for (int off = 1; off < 256; off <<= 1) {
        int x = (t >= off) ? lds[t - off] : 0;
        __syncthreads();
        lds[t] += x;
        __syncthreads();
    }
    int ex = (t > 0) ? lds[t - 1] : 0;
    #pragma unroll
    for (int j = 0; j < 4; ++j) {
        int i = gbase + j;
        if (i < N_CNT) rowptr[i] = ex;
        ex += v[j];
    }
    if (t == 255) tileSums[blockIdx.x] = lds[255];
}

// ---------------- stage 2: scan tile sums (147 <= 256) ----------------
__global__ __launch_bounds__(256) void scan_sums_kernel(
    const int* __restrict__ tileSums, int* __restrict__ tileOffs,
    int* __restrict__ rowptr) {
    __shared__ int lds[256];
    const int t = threadIdx.x;
    lds[t] = (t < N_TILES) ? tileSums[t] : 0;
    __syncthreads();
    for (int off = 1; off < 256; off <<= 1) {
        int x = (t >= off) ? lds[t - off] : 0;
        __syncthreads();
        lds[t] += x;
        __syncthreads();
    }
    if (t < N_TILES) tileOffs[t] = (t > 0) ? lds[t - 1] : 0;
    if (t == 255) rowptr[N_CNT] = lds[255];
}

// ---------------- stage 3: add tile offsets ----------------
__global__ __launch_bounds__(256) void add_offs_kernel(
    int* __restrict__ rowptr, const int* __restrict__ tileOffs) {
    const int off = tileOffs[blockIdx.x];
    const int gbase = blockIdx.x * SCAN_TILE + threadIdx.x * 4;
    #pragma unroll
    for (int j = 0; j < 4; ++j) {
        int i = gbase + j;
        if (i < N_CNT) rowptr[i] += off;
    }
}

// ---------------- CSR build: scatter packed (col,val) ----------------
__global__ void scatter_kernel(const int* __restrict__ rows, const int* __restrict__ cols,
                               const float* __restrict__ vals,
                               const int* __restrict__ rowptr, int* __restrict__ cursor,
                               int2* __restrict__ cpack) {
    int e = blockIdx.x * blockDim.x + threadIdx.x;
    if (e >= NNZ_CNT) return;
    int r = rows[e];
    int pos = rowptr[r] + atomicAdd(&cursor[r], 1);
    cpack[pos] = make_int2(cols[e], __float_as_int(vals[e]));
}

// ---------------- fused SpMM + noise + accumulate ----------------
// one wave (64 lanes) per row; lane = feature dim
// mode 0: xnext = ego; acc_out = ego            (layer 0; xnext is the cl output)
// mode 1: xnext = ego; acc_out += ego           (layer 1)
// mode 2: acc_out = (acc_out + ego) / 3         (layer 2)
__global__ __launch_bounds__(256) void layer_kernel(
    const int* __restrict__ rowptr, const int2* __restrict__ cpack,
    const float* __restrict__ xin,
    const float* __restrict__ noise_k, float* __restrict__ xnext,
    float* __restrict__ acc_out, int mode) {
    const int lane = threadIdx.x & 63;
    const int r = blockIdx.x * 4 + (threadIdx.x >> 6);
    if (r >= N_CNT) return;
    const int start = rowptr[r];
    const int end   = rowptr[r + 1];

    float acc = 0.f;
    for (int base = start; base < end; base += 64) {
        int e = base + lane;
        int2 p = make_int2(0, 0);
        if (e < end) p = cpack[e];
        int cnt = min(64, end - base);
        for (int j = 0; j < cnt; ++j) {
            int   cj = __shfl(p.x, j);
            float vj = __shfl(__int_as_float(p.y), j);
            acc += vj * xin[(size_t)cj * D_DIM + lane];
        }
    }

    // normalized noise
    float nz = noise_k[(size_t)r * D_DIM + lane];
    float sq = nz * nz;
    #pragma unroll
    for (int off = 32; off > 0; off >>= 1) sq += __shfl_xor(sq, off);
    float inv = 1.f / fmaxf(sqrtf(sq), 1e-12f);
    nz *= inv;

    float sgn = (acc > 0.f) ? 1.f : ((acc < 0.f) ? -1.f : 0.f);
    float ego = acc + sgn * nz * EPS_F;

    size_t oi = (size_t)r * D_DIM + lane;
    if (mode == 0)      { xnext[oi] = ego; acc_out[oi] = ego; }
    else if (mode == 1) { xnext[oi] = ego; acc_out[oi] += ego; }
    else                { acc_out[oi] = (acc_out[oi] + ego) * (1.f / 3.f); }
}

extern "C" void kernel_launch(void* const* d_in, const int* in_sizes, int n_in,
                              void* d_out, int out_size, void* d_ws, size_t ws_size,
                              hipStream_t stream) {
    const float* ue    = (const float*)d_in[0];
    const float* ie    = (const float*)d_in[1];
    const int*   rows  = (const int*)d_in[2];
    const int*   cols  = (const int*)d_in[3];
    const float* vals  = (const float*)d_in[4];
    const float* noise = (const float*)d_in[5];
    float* out = (float*)d_out;
    char*  ws  = (char*)d_ws;

    auto align16 = [](size_t x) { return (x + 15) & ~(size_t)15; };
    size_t off = 0;
    int*   rowptr   = (int*)(ws + off);  off = align16(off + (size_t)(N_CNT + 1) * 4);
    int*   deg      = (int*)(ws + off);  off = align16(off + (size_t)N_CNT * 4);
    int*   tileSums = (int*)(ws + off);  off = align16(off + (size_t)N_TILES * 4);
    int*   tileOffs = (int*)(ws + off);  off = align16(off + (size_t)N_TILES * 4);
    int2*  cpack    = (int2*)(ws + off); off = align16(off + (size_t)NNZ_CNT * 8);
    float* bufA     = (float*)(ws + off); off += (size_t)N_CNT * D_DIM * 4;
    (void)ws_size; (void)in_sizes; (void)n_in; (void)out_size;

    const size_t ND = (size_t)N_CNT * D_DIM;
    float* cl = out + ND;  // ego_cl region; also serves as layer-0 output / layer-1 input

    // x0 = concat(user_emb, item_emb)
    concat_kernel<<<(int)((ND / 4 + 255) / 256), 256, 0, stream>>>(ue, ie, bufA);

    // CSR build
    hipMemsetAsync(deg, 0, (size_t)N_CNT * 4, stream);
    hist_kernel<<<(NNZ_CNT / 4 + 255) / 256, 256, 0, stream>>>(rows, deg);
    partial_scan_kernel<<<N_TILES, 256, 0, stream>>>(deg, rowptr, tileSums);  // also zeroes deg
    scan_sums_kernel<<<1, 256, 0, stream>>>(tileSums, tileOffs, rowptr);
    add_offs_kernel<<<N_TILES, 256, 0, stream>>>(rowptr, tileOffs);
    scatter_kernel<<<(NNZ_CNT + 255) / 256, 256, 0, stream>>>(rows, cols, vals, rowptr,
                                                              deg, cpack);

    // 3 propagation layers (fused spmm + noise + accumulate)
    int blocks = (N_CNT + 3) / 4;
    layer_kernel<<<blocks, 256, 0, stream>>>(rowptr, cpack, bufA, noise + 0 * ND,
                                             cl, out, 0);
    layer_kernel<<<blocks, 256, 0, stream>>>(rowptr, cpack, cl,   noise + 1 * ND,
                                             bufA, out, 1);
    layer_kernel<<<blocks, 256, 0, stream>>>(rowptr, cpack, bufA, noise + 2 * ND,
                                             nullptr, out, 2);
}

// Round 3
// 1041.872 us; speedup vs baseline: 1.6409x; 1.2936x over previous
//
#include <hip/hip_runtime.h>
#include <cstdint>
#include <cstddef>

#define U_CNT 100000
#define I_CNT 50000
#define D_DIM 64
#define N_CNT (U_CNT + I_CNT)
#define NNZ_CNT 4000000
#define EPS_F 0.2f
#define SCAN_TILE 1024
#define N_TILES ((N_CNT + SCAN_TILE - 1) / SCAN_TILE)   // 147

// ---------------- CSR build: histogram (4 edges/thread) ----------------
__global__ void hist_kernel(const int* __restrict__ rows, int* __restrict__ deg) {
    int t = blockIdx.x * blockDim.x + threadIdx.x;
    if (t >= NNZ_CNT / 4) return;
    int4 r4 = ((const int4*)rows)[t];
    atomicAdd(&deg[r4.x], 1);
    atomicAdd(&deg[r4.y], 1);
    atomicAdd(&deg[r4.z], 1);
    atomicAdd(&deg[r4.w], 1);
}

// ---------------- hierarchical scan, stage 1: per-tile scan ----------------
// Scans deg into rowptr (tile-local exclusive), writes tile total, and ZEROES
// deg so it can be reused as the scatter cursor.
__global__ __launch_bounds__(256) void partial_scan_kernel(
    int* __restrict__ deg, int* __restrict__ rowptr, int* __restrict__ tileSums) {
    __shared__ int lds[256];
    const int t = threadIdx.x;
    const int gbase = blockIdx.x * SCAN_TILE + t * 4;
    int v[4];
    int s = 0;
    #pragma unroll
    for (int j = 0; j < 4; ++j) {
        int i = gbase + j;
        v[j] = (i < N_CNT) ? deg[i] : 0;
        if (i < N_CNT) deg[i] = 0;
        s += v[j];
    }
    lds[t] = s;
    __syncthreads();
    for (int off = 1; off < 256; off <<= 1) {
        int x = (t >= off) ? lds[t - off] : 0;
        __syncthreads();
        lds[t] += x;
        __syncthreads();
    }
    int ex = (t > 0) ? lds[t - 1] : 0;
    #pragma unroll
    for (int j = 0; j < 4; ++j) {
        int i = gbase + j;
        if (i < N_CNT) rowptr[i] = ex;
        ex += v[j];
    }
    if (t == 255) tileSums[blockIdx.x] = lds[255];
}

// ---------------- stage 2: scan tile sums (147 <= 256) ----------------
__global__ __launch_bounds__(256) void scan_sums_kernel(
    const int* __restrict__ tileSums, int* __restrict__ tileOffs,
    int* __restrict__ rowptr) {
    __shared__ int lds[256];
    const int t = threadIdx.x;
    lds[t] = (t < N_TILES) ? tileSums[t] : 0;
    __syncthreads();
    for (int off = 1; off < 256; off <<= 1) {
        int x = (t >= off) ? lds[t - off] : 0;
        __syncthreads();
        lds[t] += x;
        __syncthreads();
    }
    if (t < N_TILES) tileOffs[t] = (t > 0) ? lds[t - 1] : 0;
    if (t == 255) rowptr[N_CNT] = lds[255];
}

// ---------------- stage 3: add tile offsets ----------------
__global__ __launch_bounds__(256) void add_offs_kernel(
    int* __restrict__ rowptr, const int* __restrict__ tileOffs) {
    const int off = tileOffs[blockIdx.x];
    const int gbase = blockIdx.x * SCAN_TILE + threadIdx.x * 4;
    #pragma unroll
    for (int j = 0; j < 4; ++j) {
        int i = gbase + j;
        if (i < N_CNT) rowptr[i] += off;
    }
}

// ---------------- CSR build: scatter packed (col,val), 4 edges/thread ------
__global__ void scatter_kernel(const int* __restrict__ rows, const int* __restrict__ cols,
                               const float* __restrict__ vals,
                               const int* __restrict__ rowptr, int* __restrict__ cursor,
                               int2* __restrict__ cpack) {
    int t = blockIdx.x * blockDim.x + threadIdx.x;
    if (t >= NNZ_CNT / 4) return;
    int4   r4 = ((const int4*)rows)[t];
    int4   c4 = ((const int4*)cols)[t];
    float4 v4 = ((const float4*)vals)[t];
    int p;
    p = rowptr[r4.x] + atomicAdd(&cursor[r4.x], 1); cpack[p] = make_int2(c4.x, __float_as_int(v4.x));
    p = rowptr[r4.y] + atomicAdd(&cursor[r4.y], 1); cpack[p] = make_int2(c4.y, __float_as_int(v4.y));
    p = rowptr[r4.z] + atomicAdd(&cursor[r4.z], 1); cpack[p] = make_int2(c4.z, __float_as_int(v4.z));
    p = rowptr[r4.w] + atomicAdd(&cursor[r4.w], 1); cpack[p] = make_int2(c4.w, __float_as_int(v4.w));
}

__device__ __forceinline__ float sgnf(float x) {
    return (x > 0.f) ? 1.f : ((x < 0.f) ? -1.f : 0.f);
}

// ---------------- fused SpMM + noise + accumulate ----------------
// 16 lanes per row (each lane owns a float4 of D=64); 4 rows per wave,
// 16 rows per 256-thread block. Edge metadata read group-uniformly (no shfl).
// MODE 0: gather from (ue,ie) split; xnext = ego; acc_out = ego   (layer 0)
// MODE 1: gather from xin;          xnext = ego; acc_out += ego   (layer 1)
// MODE 2: gather from xin;          acc_out = (acc_out + ego)/3   (layer 2)
template <int MODE>
__global__ __launch_bounds__(256) void layer_kernel(
    const int* __restrict__ rowptr, const int2* __restrict__ cpack,
    const float4* __restrict__ xin, const float4* __restrict__ ue4,
    const float4* __restrict__ ie4,
    const float4* __restrict__ noise_k, float4* __restrict__ xnext,
    float4* __restrict__ acc_out) {
    const int gl = threadIdx.x & 15;                 // lane within 16-lane row group
    const int r  = blockIdx.x * 16 + (threadIdx.x >> 4);
    if (r >= N_CNT) return;
    const int start = rowptr[r];
    const int end   = rowptr[r + 1];

    float4 acc = make_float4(0.f, 0.f, 0.f, 0.f);
    #pragma unroll 4
    for (int e = start; e < end; ++e) {
        int2 p = cpack[e];                            // group-uniform 8B load
        float vj = __int_as_float(p.y);
        const float4* xb;
        if (MODE == 0) {
            xb = (p.x < U_CNT) ? (ue4 + (size_t)p.x * 16)
                               : (ie4 + (size_t)(p.x - U_CNT) * 16);
        } else {
            xb = xin + (size_t)p.x * 16;
        }
        float4 xr = xb[gl];                           // 256B/row, coalesced over 16 lanes
        acc.x += vj * xr.x;
        acc.y += vj * xr.y;
        acc.z += vj * xr.z;
        acc.w += vj * xr.w;
    }

    // normalized noise (norm over the row's 64 features = 16 lanes x 4 comps)
    float4 nz = noise_k[(size_t)r * 16 + gl];
    float sq = nz.x * nz.x + nz.y * nz.y + nz.z * nz.z + nz.w * nz.w;
    #pragma unroll
    for (int off = 8; off > 0; off >>= 1) sq += __shfl_xor(sq, off);
    float inv = EPS_F / fmaxf(sqrtf(sq), 1e-12f);

    float4 ego;
    ego.x = acc.x + sgnf(acc.x) * nz.x * inv;
    ego.y = acc.y + sgnf(acc.y) * nz.y * inv;
    ego.z = acc.z + sgnf(acc.z) * nz.z * inv;
    ego.w = acc.w + sgnf(acc.w) * nz.w * inv;

    size_t oi = (size_t)r * 16 + gl;
    if (MODE == 0) {
        xnext[oi] = ego;
        acc_out[oi] = ego;
    } else if (MODE == 1) {
        xnext[oi] = ego;
        float4 a = acc_out[oi];
        a.x += ego.x; a.y += ego.y; a.z += ego.z; a.w += ego.w;
        acc_out[oi] = a;
    } else {
        float4 a = acc_out[oi];
        a.x = (a.x + ego.x) * (1.f / 3.f);
        a.y = (a.y + ego.y) * (1.f / 3.f);
        a.z = (a.z + ego.z) * (1.f / 3.f);
        a.w = (a.w + ego.w) * (1.f / 3.f);
        acc_out[oi] = a;
    }
}

extern "C" void kernel_launch(void* const* d_in, const int* in_sizes, int n_in,
                              void* d_out, int out_size, void* d_ws, size_t ws_size,
                              hipStream_t stream) {
    const float* ue    = (const float*)d_in[0];
    const float* ie    = (const float*)d_in[1];
    const int*   rows  = (const int*)d_in[2];
    const int*   cols  = (const int*)d_in[3];
    const float* vals  = (const float*)d_in[4];
    const float* noise = (const float*)d_in[5];
    float* out = (float*)d_out;
    char*  ws  = (char*)d_ws;

    auto align16 = [](size_t x) { return (x + 15) & ~(size_t)15; };
    size_t off = 0;
    int*   rowptr   = (int*)(ws + off);  off = align16(off + (size_t)(N_CNT + 1) * 4);
    int*   deg      = (int*)(ws + off);  off = align16(off + (size_t)N_CNT * 4);
    int*   tileSums = (int*)(ws + off);  off = align16(off + (size_t)N_TILES * 4);
    int*   tileOffs = (int*)(ws + off);  off = align16(off + (size_t)N_TILES * 4);
    int2*  cpack    = (int2*)(ws + off); off = align16(off + (size_t)NNZ_CNT * 8);
    float* bufA     = (float*)(ws + off); off += (size_t)N_CNT * D_DIM * 4;
    (void)ws_size; (void)in_sizes; (void)n_in; (void)out_size;

    const size_t ND = (size_t)N_CNT * D_DIM;
    float* cl = out + ND;  // ego_cl region; doubles as layer-0 output / layer-1 input

    // CSR build
    hipMemsetAsync(deg, 0, (size_t)N_CNT * 4, stream);
    hist_kernel<<<(NNZ_CNT / 4 + 255) / 256, 256, 0, stream>>>(rows, deg);
    partial_scan_kernel<<<N_TILES, 256, 0, stream>>>(deg, rowptr, tileSums);  // zeroes deg
    scan_sums_kernel<<<1, 256, 0, stream>>>(tileSums, tileOffs, rowptr);
    add_offs_kernel<<<N_TILES, 256, 0, stream>>>(rowptr, tileOffs);
    scatter_kernel<<<(NNZ_CNT / 4 + 255) / 256, 256, 0, stream>>>(rows, cols, vals, rowptr,
                                                                  deg, cpack);

    // 3 propagation layers (fused spmm + noise + accumulate), 16 rows/block
    int blocks = (N_CNT + 15) / 16;
    layer_kernel<0><<<blocks, 256, 0, stream>>>(rowptr, cpack, nullptr,
                                                (const float4*)ue, (const float4*)ie,
                                                (const float4*)(noise + 0 * ND),
                                                (float4*)cl, (float4*)out);
    layer_kernel<1><<<blocks, 256, 0, stream>>>(rowptr, cpack, (const float4*)cl,
                                                nullptr, nullptr,
                                                (const float4*)(noise + 1 * ND),
                                                (float4*)bufA, (float4*)out);
    layer_kernel<2><<<blocks, 256, 0, stream>>>(rowptr, cpack, (const float4*)bufA,
                                                nullptr, nullptr,
                                                (const float4*)(noise + 2 * ND),
                                                nullptr, (float4*)out);
}